// Round 10
// baseline (363.397 us; speedup 1.0000x reference)
//
#include <hip/hip_runtime.h>
#include <math.h>

#define HWSZ (512*512)
#define EPSV 1e-5f

typedef _Float16 h8 __attribute__((ext_vector_type(8)));
typedef _Float16 h4 __attribute__((ext_vector_type(4)));
typedef _Float16 h2 __attribute__((ext_vector_type(2)));
typedef float    f32x4 __attribute__((ext_vector_type(4)));

__device__ __forceinline__ h8 as_h8(uint4 u) { return __builtin_bit_cast(h8, u); }
__device__ __forceinline__ uint4 as_u4(h8 v) { return __builtin_bit_cast(uint4, v); }

// XCD-contiguous bijective remap (kept on conv3x3 only).
__device__ __forceinline__ int xcd_swz_4096(int bid) {
    return (bid & 7) * 512 + (bid >> 3);
}

// ---------------------------------------------------------------------------
// NCHW fp32 -> HWC fp16. 64 px x 64 ch tile via LDS; packed u32 stores.
// ---------------------------------------------------------------------------
__global__ __launch_bounds__(256) void to_hwc_f16(const float* __restrict__ in,
                                                  unsigned* __restrict__ out32) {
    __shared__ float T[64 * 65];
    int tid = threadIdx.x;
    int pbase = blockIdx.x * 64;
    int p = tid & 63, cg = tid >> 6;
#pragma unroll
    for (int j = 0; j < 16; ++j) {
        int c = cg * 16 + j;
        T[p * 65 + c] = in[c * HWSZ + pbase + p];
    }
    __syncthreads();
    int px = tid >> 2, cb = (tid & 3) * 16;
#pragma unroll
    for (int j = 0; j < 8; ++j) {
        int c = cb + 2 * j;
        h2 v = {(_Float16)T[px * 65 + c], (_Float16)T[px * 65 + c + 1]};
        out32[(pbase + px) * 32 + (c >> 1)] = __builtin_bit_cast(unsigned, v);
    }
}

// ---------------------------------------------------------------------------
// Weight prep. dcn: [o][c][3][3] -> [k][slice(8)][o][8ch] fp16 (coalesced
// B-frag loads). off: [18][c][3][3] -> [k][o=32 pad][c].
// ---------------------------------------------------------------------------
__global__ __launch_bounds__(256) void prep_all(
        const float* __restrict__ dw1, const float* __restrict__ dw2,
        const float* __restrict__ ow1, const float* __restrict__ ow2,
        _Float16* __restrict__ wT1, _Float16* __restrict__ wT2,
        _Float16* __restrict__ wTo1, _Float16* __restrict__ wTo2) {
    int i = blockIdx.x * 256 + threadIdx.x;
    if (i < 36864) {
        int k = i / 4096, r = i % 4096;
        int s = r >> 9, o = (r >> 3) & 63, j = r & 7;
        int c = (s >> 2) * 32 + (s & 3) * 8 + j;
        wT1[i] = (_Float16)dw1[(o * 64 + c) * 9 + k];
    } else if (i < 73728) {
        int ii = i - 36864;
        int k = ii / 4096, r = ii % 4096;
        int s = r >> 9, o = (r >> 3) & 63, j = r & 7;
        int c = (s >> 2) * 32 + (s & 3) * 8 + j;
        wT2[ii] = (_Float16)dw2[(o * 64 + c) * 9 + k];
    } else if (i < 92160) {
        int j = i - 73728;
        int k = j / 2048, r = j % 2048, o = r >> 6, c = r & 63;
        wTo1[k * 2048 + o * 64 + c] = (_Float16)((o < 18) ? ow1[(o * 64 + c) * 9 + k] : 0.f);
    } else if (i < 110592) {
        int j = i - 92160;
        int k = j / 2048, r = j % 2048, o = r >> 6, c = r & 63;
        wTo2[k * 2048 + o * 64 + c] = (_Float16)((o < 18) ? ow2[(o * 64 + c) * 9 + k] : 0.f);
    }
}

// ---------------------------------------------------------------------------
// 3x3 conv 64->18 (pad 32) via MFMA (unchanged).
// ---------------------------------------------------------------------------
__global__ __launch_bounds__(256, 4) void conv3x3_off_mfma(
        const _Float16* __restrict__ in, const _Float16* __restrict__ wTo,
        const float* __restrict__ bias, _Float16* __restrict__ off) {
    __shared__ uint4 TILE[3 * 66 * 8];   // 25.3 KB

    int tid = threadIdx.x;
    int pbase = xcd_swz_4096(blockIdx.x) * 64;
    int y = pbase >> 9, xblk = pbase & 511;
    int l = tid & 63, wv = tid >> 6;
    int lq = l & 15, quad = l >> 4;
    int wn = wv & 1, wm = wv >> 1;     // wave tile: 32 px x 16 n

    h8 breg[18];
#pragma unroll
    for (int k = 0; k < 9; ++k)
#pragma unroll
        for (int kc = 0; kc < 2; ++kc)
            breg[k * 2 + kc] = *(const h8*)(wTo + k * 2048 + (wn * 16 + lq) * 64 + kc * 32 + quad * 8);

    uint4 v[7];
#pragma unroll
    for (int i = 0; i < 7; ++i) {
        int t = tid + 256 * i;
        int row = t / 528, r = t - row * 528;
        int col = r >> 3, cc = r & 7;
        int sy = y + row - 1, sx = xblk + col - 1;
        bool ok = (t < 1584) && ((unsigned)sy < 512u) && ((unsigned)sx < 512u);
        v[i] = ok ? *(const uint4*)(in + (sy * 512 + sx) * 64 + cc * 8)
                  : make_uint4(0u, 0u, 0u, 0u);
    }
#pragma unroll
    for (int i = 0; i < 7; ++i) {
        int t = tid + 256 * i;
        if (t < 1584) {
            int row = t / 528, r = t - row * 528;
            int col = r >> 3, cc = r & 7;
            TILE[(row * 66 + col) * 8 + (cc ^ (col & 7))] = v[i];
        }
    }
    __syncthreads();

    f32x4 zero = {0.f, 0.f, 0.f, 0.f};
    f32x4 acc[2]; acc[0] = zero; acc[1] = zero;

#pragma unroll
    for (int k = 0; k < 9; ++k) {
        int ky = k / 3, kx = k % 3;
#pragma unroll
        for (int kc = 0; kc < 2; ++kc) {
#pragma unroll
            for (int tm = 0; tm < 2; ++tm) {
                int col = kx + wm * 32 + tm * 16 + lq;
                int cc0 = kc * 4 + quad;
                h8 a = as_h8(TILE[(ky * 66 + col) * 8 + (cc0 ^ (col & 7))]);
                acc[tm] = __builtin_amdgcn_mfma_f32_16x16x32_f16(a, breg[k * 2 + kc], acc[tm], 0, 0, 0);
            }
        }
    }

    int n = wn * 16 + lq;
    if (n < 18) {
        float bb = bias[n];
#pragma unroll
        for (int tm = 0; tm < 2; ++tm)
#pragma unroll
            for (int reg = 0; reg < 4; ++reg) {
                int px = wm * 32 + tm * 16 + quad * 4 + reg;
                off[(pbase + px) * 18 + n] = (_Float16)(acc[tm][reg] + bb);
            }
    }
}

// ---------------------------------------------------------------------------
// Deformable conv 3x3 64->64 + bias + BN + ReLU via f16 MFMA. (r9 window
// structure: 8x8 tile, 14x14 LDS window, wave-local blend->A-frags.)
// r10: (a) delta-encoded corner meta {wp00, flags, y0c, x0c}: fast path is
// 3 adds + per-corner {and,xor,shl-or} and HI-half addr = LO addr ^ 64
// (slot algebra (quad+4)^s == (quad^s)^4) -- cuts the 40% VALUBusy that
// dominated r9. Out-of-window corners (|off|>1, 4-sigma tail, ~60/layer)
// keep the exact global fallback. (b) FINAL template: fuse conv1x1 --
// per-lane partial dot, shfl_xor reduce over the 16 lanes of a pixel,
// lane 0 writes fp32; h2 write eliminated.
// ---------------------------------------------------------------------------
template<int FINAL>
__global__ __launch_bounds__(256, 3) void dcn_fused(
        const _Float16* __restrict__ in, const _Float16* __restrict__ off,
        const _Float16* __restrict__ wTd, const float* __restrict__ bias,
        const float* __restrict__ gamma, const float* __restrict__ beta,
        const float* __restrict__ mean, const float* __restrict__ var,
        _Float16* __restrict__ out,
        const float* __restrict__ w1x1, const float* __restrict__ b1x1,
        float* __restrict__ outf) {
    __shared__ uint4  WIN[196 * 8];    // 25.1 KB: 14x14 px window, swizzled
    __shared__ h4     SW9[9 * 64];     // bilinear weights
    __shared__ short4 SI9[9 * 64];     // {wp00, flags, y0c, x0c}
    __shared__ float  scl_s[64], sh_s[64];

    int tid = threadIdx.x;
    int bid = blockIdx.x;
    int ty = bid >> 6, tx = bid & 63;        // 64x64 tiles of 8x8 px
    int r0 = ty * 8, c0 = tx * 8;
    int wr0 = r0 - 3, wc0 = c0 - 3;          // window origin

    // ---- per-pixel bilinear meta for all 9 taps
    for (int t = tid; t < 576; t += 256) {
        int p = t & 63, k = t >> 6;
        int pr = p >> 3, pc = p & 7;
        int y = r0 + pr, x = c0 + pc;
        int gp = y * 512 + x;
        h2 dv = *(const h2*)(off + gp * 18 + 2 * k);
        float py = (float)(y + k / 3 - 1) + (float)dv[0];
        float px = (float)(x + k % 3 - 1) + (float)dv[1];
        float y0f = floorf(py), x0f = floorf(px);
        float wy = py - y0f, wx = px - x0f;
        int y0 = (int)y0f, x0 = (int)x0f;
        int y1 = y0 + 1, x1 = x0 + 1;
        float vy0 = ((unsigned)y0 < 512u) ? 1.f : 0.f;
        float vy1 = ((unsigned)y1 < 512u) ? 1.f : 0.f;
        float vx0 = ((unsigned)x0 < 512u) ? 1.f : 0.f;
        float vx1 = ((unsigned)x1 < 512u) ? 1.f : 0.f;
        SW9[t] = (h4){(_Float16)((1.f - wy) * (1.f - wx) * vy0 * vx0),
                      (_Float16)((1.f - wy) * wx * vy0 * vx1),
                      (_Float16)(wy * (1.f - wx) * vy1 * vx0),
                      (_Float16)(wy * wx * vy1 * vx1)};
        int y0c = min(max(y0, 0), 511), y1c = min(max(y1, 0), 511);
        int x0c = min(max(x0, 0), 511), x1c = min(max(x1, 0), 511);
        int wy0 = y0c - wr0, wx0 = x0c - wc0;
        int wy1 = y1c - wr0, wx1 = x1c - wc0;
        int dx = x1c - x0c;                  // 0 or 1
        int dyf = (y1c != y0c) ? 2 : 0;
        bool inwin = ((unsigned)wy0 < 14u) && ((unsigned)wy1 < 14u) &&
                     ((unsigned)wx0 < 14u) && ((unsigned)wx1 < 14u);
        int flags = dx | dyf | (inwin ? 4 : 0);
        SI9[t] = make_short4((short)(wy0 * 14 + wx0), (short)flags,
                             (short)y0c, (short)x0c);
    }
    if (tid < 64) {
        float s = gamma[tid] * rsqrtf(var[tid] + EPSV);
        scl_s[tid] = s;
        sh_s[tid] = beta[tid] - mean[tid] * s + bias[tid] * s;
    }

    // ---- stage 14x14 window: 1568 16B tasks in 7 rounds
    uint4 sv[7];
#pragma unroll
    for (int i = 0; i < 7; ++i) {
        int t = tid + 256 * i;
        int wp = t >> 3, cc = t & 7;
        int wi = wp / 14, wj = wp - wi * 14;
        int sy = wr0 + wi, sx = wc0 + wj;
        bool ok = (t < 1568) && ((unsigned)sy < 512u) && ((unsigned)sx < 512u);
        sv[i] = ok ? *(const uint4*)(in + ((sy << 9) + sx) * 64 + cc * 8)
                   : make_uint4(0u, 0u, 0u, 0u);
    }
#pragma unroll
    for (int i = 0; i < 7; ++i) {
        int t = tid + 256 * i;
        if (t < 1568) {
            int wp = t >> 3, cc = t & 7;
            WIN[wp * 8 + (cc ^ (wp & 7))] = sv[i];
        }
    }
    __syncthreads();   // window + meta ready (the only barrier)

    int l = tid & 63, wv = tid >> 6;
    int lq = l & 15, quad = l >> 4;
    int pxl = wv * 16 + lq;           // this lane's local pixel (0..63)
    const char* Wb = (const char*)WIN;
    int qsl = quad << 4;              // LO slot byte base component

    f32x4 zero = {0.f, 0.f, 0.f, 0.f};
    f32x4 acc[4];
    acc[0] = zero; acc[1] = zero; acc[2] = zero; acc[3] = zero;

#pragma unroll
    for (int k = 0; k < 9; ++k) {
        // B-frags: [k][slice][o][8] layout -> quarter-wave 256B contiguous
        const _Float16* wk = wTd + k * 4096;
        h8 bl[4], bh[4];
#pragma unroll
        for (int nb = 0; nb < 4; ++nb) {
            bl[nb] = *(const h8*)(wk + (quad * 64 + nb * 16 + lq) * 8);
            bh[nb] = *(const h8*)(wk + ((quad + 4) * 64 + nb * 16 + lq) * 8);
        }
        short4 s = SI9[k * 64 + pxl];
        h4 w = SW9[k * 64 + pxl];
        h8 c0l, c0h, c1l, c1h, c2l, c2h, c3l, c3h;
        if (s.y & 4) {
            // fast path: all 4 corners in LDS window
            int dx  = s.y & 1;
            int dy  = (s.y & 2) ? 14 : 0;
            int wp0 = s.x;
            int wp1 = wp0 + dx, wp2 = wp0 + dy, wp3 = wp2 + dx;
            int b0 = (wp0 << 7) + (((quad ^ (wp0 & 7))) << 4);
            int b1 = (wp1 << 7) + (((quad ^ (wp1 & 7))) << 4);
            int b2 = (wp2 << 7) + (((quad ^ (wp2 & 7))) << 4);
            int b3 = (wp3 << 7) + (((quad ^ (wp3 & 7))) << 4);
            c0l = *(const h8*)(Wb + b0); c0h = *(const h8*)(Wb + (b0 ^ 64));
            c1l = *(const h8*)(Wb + b1); c1h = *(const h8*)(Wb + (b1 ^ 64));
            c2l = *(const h8*)(Wb + b2); c2h = *(const h8*)(Wb + (b2 ^ 64));
            c3l = *(const h8*)(Wb + b3); c3h = *(const h8*)(Wb + (b3 ^ 64));
        } else {
            // rare fallback: exact global loads from clamped coords
            int dx = s.y & 1, dyr = (s.y >> 1) & 1;
            int y0c = s.z, x0c = s.w;
            const _Float16* g00 = in + (((y0c) << 9) + x0c) * 64 + quad * 8;
            const _Float16* g01 = in + (((y0c) << 9) + x0c + dx) * 64 + quad * 8;
            const _Float16* g10 = in + (((y0c + dyr) << 9) + x0c) * 64 + quad * 8;
            const _Float16* g11 = in + (((y0c + dyr) << 9) + x0c + dx) * 64 + quad * 8;
            c0l = *(const h8*)g00; c0h = *(const h8*)(g00 + 32);
            c1l = *(const h8*)g01; c1h = *(const h8*)(g01 + 32);
            c2l = *(const h8*)g10; c2h = *(const h8*)(g10 + 32);
            c3l = *(const h8*)g11; c3h = *(const h8*)(g11 + 32);
        }
        h8 alo = c0l * w[0] + c1l * w[1] + c2l * w[2] + c3l * w[3];
        h8 ahi = c0h * w[0] + c1h * w[1] + c2h * w[2] + c3h * w[3];
#pragma unroll
        for (int nb = 0; nb < 4; ++nb)
            acc[nb] = __builtin_amdgcn_mfma_f32_16x16x32_f16(alo, bl[nb], acc[nb], 0, 0, 0);
#pragma unroll
        for (int nb = 0; nb < 4; ++nb)
            acc[nb] = __builtin_amdgcn_mfma_f32_16x16x32_f16(ahi, bh[nb], acc[nb], 0, 0, 0);
    }

    // ---- epilogue
    float sc[4], sh[4];
#pragma unroll
    for (int nb = 0; nb < 4; ++nb) {
        sc[nb] = scl_s[nb * 16 + lq];
        sh[nb] = sh_s[nb * 16 + lq];
    }
    if constexpr (FINAL) {
        // fused 1x1 conv: per-lane partial dot over its 4 oc, reduce over
        // the 16 lanes (lq) that share a pixel, lane lq==0 writes fp32.
        float wv4[4];
#pragma unroll
        for (int nb = 0; nb < 4; ++nb) wv4[nb] = w1x1[nb * 16 + lq];
        float bb = b1x1[0];
#pragma unroll
        for (int reg = 0; reg < 4; ++reg) {
            float v = 0.f;
#pragma unroll
            for (int nb = 0; nb < 4; ++nb)
                v += fmaxf(fmaf(acc[nb][reg], sc[nb], sh[nb]), 0.f) * wv4[nb];
            v += __shfl_xor(v, 1, 16);
            v += __shfl_xor(v, 2, 16);
            v += __shfl_xor(v, 4, 16);
            v += __shfl_xor(v, 8, 16);
            if (lq == 0) {
                int p_out = wv * 16 + quad * 4 + reg;
                int gp = (r0 + (p_out >> 3)) * 512 + c0 + (p_out & 7);
                outf[gp] = v + bb;
            }
        }
    } else {
#pragma unroll
        for (int nb = 0; nb < 4; ++nb) {
#pragma unroll
            for (int reg = 0; reg < 4; ++reg) {
                int p_out = wv * 16 + quad * 4 + reg;
                int gp = (r0 + (p_out >> 3)) * 512 + c0 + (p_out & 7);
                out[gp * 64 + nb * 16 + lq] =
                    (_Float16)fmaxf(fmaf(acc[nb][reg], sc[nb], sh[nb]), 0.f);
            }
        }
    }
}

// ---------------------------------------------------------------------------
extern "C" void kernel_launch(void* const* d_in, const int* in_sizes, int n_in,
                              void* d_out, int out_size, void* d_ws, size_t ws_size,
                              hipStream_t stream) {
    const float* x      = (const float*)d_in[0];
    const float* off1_w = (const float*)d_in[1];
    const float* off1_b = (const float*)d_in[2];
    const float* dcn1_w = (const float*)d_in[3];
    const float* dcn1_b = (const float*)d_in[4];
    const float* bn1_g  = (const float*)d_in[5];
    const float* bn1_be = (const float*)d_in[6];
    const float* bn1_m  = (const float*)d_in[7];
    const float* bn1_v  = (const float*)d_in[8];
    const float* off2_w = (const float*)d_in[9];
    const float* off2_b = (const float*)d_in[10];
    const float* dcn2_w = (const float*)d_in[11];
    const float* dcn2_b = (const float*)d_in[12];
    const float* bn2_g  = (const float*)d_in[13];
    const float* bn2_be = (const float*)d_in[14];
    const float* bn2_m  = (const float*)d_in[15];
    const float* bn2_v  = (const float*)d_in[16];
    const float* conv_w = (const float*)d_in[17];
    const float* conv_b = (const float*)d_in[18];
    float* out = (float*)d_out;

    char* ws = (char*)d_ws;
    _Float16* xh   = (_Float16*)ws;                       // 32 MiB
    _Float16* h1   = (_Float16*)(ws + 33554432);          // 32 MiB
    _Float16* offb = (_Float16*)(ws + 2 * 33554432);      // 9 MiB
    _Float16* wT1  = (_Float16*)(ws + 2 * 33554432 + 9437184);
    _Float16* wT2  = wT1 + 36864;
    _Float16* wTo1 = wT2 + 36864;
    _Float16* wTo2 = wTo1 + 18432;

    prep_all<<<432, 256, 0, stream>>>(dcn1_w, dcn2_w, off1_w, off2_w,
                                      wT1, wT2, wTo1, wTo2);
    to_hwc_f16<<<4096, 256, 0, stream>>>(x, (unsigned*)xh);

    conv3x3_off_mfma<<<4096, 256, 0, stream>>>(xh, wTo1, off1_b, offb);
    dcn_fused<0><<<4096, 256, 0, stream>>>(xh, offb, wT1, dcn1_b,
                                           bn1_g, bn1_be, bn1_m, bn1_v, h1,
                                           nullptr, nullptr, nullptr);
    conv3x3_off_mfma<<<4096, 256, 0, stream>>>(h1, wTo2, off2_b, offb);
    dcn_fused<1><<<4096, 256, 0, stream>>>(h1, offb, wT2, dcn2_b,
                                           bn2_g, bn2_be, bn2_m, bn2_v, nullptr,
                                           conv_w, conv_b, out);
}